// Round 1
// baseline (307.501 us; speedup 1.0000x reference)
//
#include <hip/hip_runtime.h>

#define POOLED 7
#define RATIO 2

__global__ __launch_bounds__(256)
void roi_align_kernel(const float* __restrict__ rois,
                      const float* __restrict__ feat,
                      const int* __restrict__ stride_ptr,
                      int B, int C, int H, int W, int N,
                      float* __restrict__ out) {
    const int total = N * C * POOLED * POOLED;
    int idx = blockIdx.x * blockDim.x + threadIdx.x;
    if (idx >= total) return;

    const float scale = 1.0f / (float)stride_ptr[0];

    int pw = idx % POOLED;
    int ph = (idx / POOLED) % POOLED;
    int c  = (idx / (POOLED * POOLED)) % C;
    int n  = idx / (POOLED * POOLED * C);

    const float* r = rois + (size_t)n * 5;
    int b = (int)r[0];
    float x1 = r[1] * scale;
    float y1 = r[2] * scale;
    float x2 = r[3] * scale;
    float y2 = r[4] * scale;
    float roi_w = fmaxf(x2 - x1, 1.0f);
    float roi_h = fmaxf(y2 - y1, 1.0f);
    float bin_w = roi_w / (float)POOLED;
    float bin_h = roi_h / (float)POOLED;

    const float* plane = feat + ((size_t)b * C + c) * (size_t)(H * W);

    float acc = 0.0f;
    #pragma unroll
    for (int sy = 0; sy < RATIO; ++sy) {
        // sample y coordinate: y = y1 + ((ph*RATIO + sy + 0.5)/RATIO) * bin_h
        float iy = ((float)(ph * RATIO + sy) + 0.5f) / (float)RATIO;
        float yy = y1 + iy * bin_h;
        bool vy = (yy > -1.0f) && (yy < (float)H);
        float cy = fminf(fmaxf(yy, 0.0f), (float)(H - 1));
        int y0 = (int)floorf(cy);
        if (y0 > H - 1) y0 = H - 1;
        int y1i = min(y0 + 1, H - 1);
        float fy = cy - (float)y0;
        float hy = 1.0f - fy;

        #pragma unroll
        for (int sx = 0; sx < RATIO; ++sx) {
            float ix = ((float)(pw * RATIO + sx) + 0.5f) / (float)RATIO;
            float xx = x1 + ix * bin_w;
            bool vx = (xx > -1.0f) && (xx < (float)W);
            if (!(vy && vx)) continue;
            float cx = fminf(fmaxf(xx, 0.0f), (float)(W - 1));
            int x0 = (int)floorf(cx);
            if (x0 > W - 1) x0 = W - 1;
            int x1i = min(x0 + 1, W - 1);
            float fx = cx - (float)x0;
            float hx = 1.0f - fx;

            float v00 = plane[y0  * W + x0 ];
            float v01 = plane[y0  * W + x1i];
            float v10 = plane[y1i * W + x0 ];
            float v11 = plane[y1i * W + x1i];

            acc += hy * hx * v00 + hy * fx * v01 + fy * hx * v10 + fy * fx * v11;
        }
    }

    out[idx] = acc * (1.0f / (float)(RATIO * RATIO));
}

extern "C" void kernel_launch(void* const* d_in, const int* in_sizes, int n_in,
                              void* d_out, int out_size, void* d_ws, size_t ws_size,
                              hipStream_t stream) {
    const float* rois = (const float*)d_in[0];
    const float* feat = (const float*)d_in[1];
    const int* stride_ptr = (const int*)d_in[2];

    const int N = in_sizes[0] / 5;
    const int C = 256;
    const int H = 192;
    const int W = 192;
    const int B = in_sizes[1] / (C * H * W);

    float* out = (float*)d_out;

    const int total = N * C * POOLED * POOLED;
    const int block = 256;
    const int grid = (total + block - 1) / block;

    roi_align_kernel<<<grid, block, 0, stream>>>(rois, feat, stride_ptr,
                                                 B, C, H, W, N, out);
}

// Round 2
// 300.483 us; speedup vs baseline: 1.0234x; 1.0234x over previous
//
#include <hip/hip_runtime.h>

#define POOLED 7
#define RATIO 2

constexpr int C_ = 256;
constexpr int H_ = 192;
constexpr int W_ = 192;
constexpr int P_ = H_ * W_;   // pixels per plane

// ---------------- NCHW -> NHWC transpose (per batch: (C,P) -> (P,C)) -------
__global__ __launch_bounds__(256)
void nchw_to_nhwc_kernel(const float* __restrict__ in, float* __restrict__ outT) {
    __shared__ float tile[32][33];
    const int b  = blockIdx.z;
    const int p0 = blockIdx.x * 32;   // pixel tile origin
    const int c0 = blockIdx.y * 32;   // channel tile origin
    const float* src = in   + (size_t)b * C_ * P_;
    float*       dst = outT + (size_t)b * P_ * C_;

    const int tx = threadIdx.x;       // 0..31
    const int px = p0 + tx;
    #pragma unroll
    for (int i = threadIdx.y; i < 32; i += 8) {
        tile[i][tx] = src[(size_t)(c0 + i) * P_ + px];
    }
    __syncthreads();
    const int cx = c0 + tx;
    #pragma unroll
    for (int i = threadIdx.y; i < 32; i += 8) {
        dst[(size_t)(p0 + i) * C_ + cx] = tile[tx][i];
    }
}

// ---------------- RoIAlign on NHWC feature ---------------------------------
__global__ __launch_bounds__(256)
void roi_align_nhwc_kernel(const float* __restrict__ rois,
                           const float* __restrict__ featT,   // (B,H,W,C)
                           const int* __restrict__ stride_ptr,
                           float* __restrict__ out, int N) {
    const int n    = blockIdx.x;
    const int lane = threadIdx.x & 63;
    const int wave = threadIdx.x >> 6;

    const float scale = 1.0f / (float)stride_ptr[0];
    const float* r = rois + (size_t)n * 5;
    const int   b  = (int)r[0];
    const float x1 = r[1] * scale;
    const float y1 = r[2] * scale;
    const float x2 = r[3] * scale;
    const float y2 = r[4] * scale;
    const float bin_w = fmaxf(x2 - x1, 1.0f) * (1.0f / (float)POOLED);
    const float bin_h = fmaxf(y2 - y1, 1.0f) * (1.0f / (float)POOLED);

    const float4* fbase = (const float4*)featT + (size_t)b * P_ * (C_ / 4);

    for (int bin = wave; bin < POOLED * POOLED; bin += 4) {
        const int ph = bin / POOLED;
        const int pw = bin - ph * POOLED;

        float4 acc = make_float4(0.f, 0.f, 0.f, 0.f);

        #pragma unroll
        for (int sy = 0; sy < RATIO; ++sy) {
            const float yy = y1 + ((float)(ph * RATIO + sy) + 0.5f) * (1.0f / RATIO) * bin_h;
            const bool  vy = (yy > -1.0f) && (yy < (float)H_);
            float cy = fminf(fmaxf(yy, 0.0f), (float)(H_ - 1));
            int   y0 = (int)floorf(cy);
            if (y0 > H_ - 1) y0 = H_ - 1;
            const int   y1i = min(y0 + 1, H_ - 1);
            const float fy  = cy - (float)y0;
            const float hy  = 1.0f - fy;

            #pragma unroll
            for (int sx = 0; sx < RATIO; ++sx) {
                const float xx = x1 + ((float)(pw * RATIO + sx) + 0.5f) * (1.0f / RATIO) * bin_w;
                const bool  vx = (xx > -1.0f) && (xx < (float)W_);
                if (!(vy && vx)) continue;
                float cx = fminf(fmaxf(xx, 0.0f), (float)(W_ - 1));
                int   x0 = (int)floorf(cx);
                if (x0 > W_ - 1) x0 = W_ - 1;
                const int   x1i = min(x0 + 1, W_ - 1);
                const float fx  = cx - (float)x0;
                const float hx  = 1.0f - fx;

                const float w00 = hy * hx, w01 = hy * fx, w10 = fy * hx, w11 = fy * fx;

                const float4 v00 = fbase[(size_t)(y0  * W_ + x0 ) * (C_ / 4) + lane];
                const float4 v01 = fbase[(size_t)(y0  * W_ + x1i) * (C_ / 4) + lane];
                const float4 v10 = fbase[(size_t)(y1i * W_ + x0 ) * (C_ / 4) + lane];
                const float4 v11 = fbase[(size_t)(y1i * W_ + x1i) * (C_ / 4) + lane];

                acc.x = fmaf(w00, v00.x, fmaf(w01, v01.x, fmaf(w10, v10.x, fmaf(w11, v11.x, acc.x))));
                acc.y = fmaf(w00, v00.y, fmaf(w01, v01.y, fmaf(w10, v10.y, fmaf(w11, v11.y, acc.y))));
                acc.z = fmaf(w00, v00.z, fmaf(w01, v01.z, fmaf(w10, v10.z, fmaf(w11, v11.z, acc.z))));
                acc.w = fmaf(w00, v00.w, fmaf(w01, v01.w, fmaf(w10, v10.w, fmaf(w11, v11.w, acc.w))));
            }
        }

        acc.x *= 0.25f; acc.y *= 0.25f; acc.z *= 0.25f; acc.w *= 0.25f;

        // out[n][c][ph][pw], c = 4*lane..4*lane+3
        float* op = out + (size_t)n * (C_ * POOLED * POOLED) + bin;
        const int cb = lane * 4;
        op[(size_t)(cb + 0) * (POOLED * POOLED)] = acc.x;
        op[(size_t)(cb + 1) * (POOLED * POOLED)] = acc.y;
        op[(size_t)(cb + 2) * (POOLED * POOLED)] = acc.z;
        op[(size_t)(cb + 3) * (POOLED * POOLED)] = acc.w;
    }
}

// ---------------- Fallback (round-1, NCHW direct) ---------------------------
__global__ __launch_bounds__(256)
void roi_align_kernel(const float* __restrict__ rois,
                      const float* __restrict__ feat,
                      const int* __restrict__ stride_ptr,
                      int B, int C, int H, int W, int N,
                      float* __restrict__ out) {
    const int total = N * C * POOLED * POOLED;
    int idx = blockIdx.x * blockDim.x + threadIdx.x;
    if (idx >= total) return;

    const float scale = 1.0f / (float)stride_ptr[0];

    int pw = idx % POOLED;
    int ph = (idx / POOLED) % POOLED;
    int c  = (idx / (POOLED * POOLED)) % C;
    int n  = idx / (POOLED * POOLED * C);

    const float* r = rois + (size_t)n * 5;
    int b = (int)r[0];
    float x1 = r[1] * scale;
    float y1 = r[2] * scale;
    float x2 = r[3] * scale;
    float y2 = r[4] * scale;
    float bin_w = fmaxf(x2 - x1, 1.0f) / (float)POOLED;
    float bin_h = fmaxf(y2 - y1, 1.0f) / (float)POOLED;

    const float* plane = feat + ((size_t)b * C + c) * (size_t)(H * W);

    float acc = 0.0f;
    #pragma unroll
    for (int sy = 0; sy < RATIO; ++sy) {
        float iy = ((float)(ph * RATIO + sy) + 0.5f) / (float)RATIO;
        float yy = y1 + iy * bin_h;
        bool vy = (yy > -1.0f) && (yy < (float)H);
        float cy = fminf(fmaxf(yy, 0.0f), (float)(H - 1));
        int y0 = (int)floorf(cy);
        if (y0 > H - 1) y0 = H - 1;
        int y1i = min(y0 + 1, H - 1);
        float fy = cy - (float)y0;
        float hy = 1.0f - fy;

        #pragma unroll
        for (int sx = 0; sx < RATIO; ++sx) {
            float ix = ((float)(pw * RATIO + sx) + 0.5f) / (float)RATIO;
            float xx = x1 + ix * bin_w;
            bool vx = (xx > -1.0f) && (xx < (float)W);
            if (!(vy && vx)) continue;
            float cx = fminf(fmaxf(xx, 0.0f), (float)(W - 1));
            int x0 = (int)floorf(cx);
            if (x0 > W - 1) x0 = W - 1;
            int x1i = min(x0 + 1, W - 1);
            float fx = cx - (float)x0;
            float hx = 1.0f - fx;

            float v00 = plane[y0  * W + x0 ];
            float v01 = plane[y0  * W + x1i];
            float v10 = plane[y1i * W + x0 ];
            float v11 = plane[y1i * W + x1i];

            acc += hy * hx * v00 + hy * fx * v01 + fy * hx * v10 + fy * fx * v11;
        }
    }

    out[idx] = acc * 0.25f;
}

extern "C" void kernel_launch(void* const* d_in, const int* in_sizes, int n_in,
                              void* d_out, int out_size, void* d_ws, size_t ws_size,
                              hipStream_t stream) {
    const float* rois = (const float*)d_in[0];
    const float* feat = (const float*)d_in[1];
    const int* stride_ptr = (const int*)d_in[2];

    const int N = in_sizes[0] / 5;
    const int B = in_sizes[1] / (C_ * P_);
    float* out = (float*)d_out;

    const size_t need = (size_t)B * P_ * C_ * sizeof(float);
    if (ws_size >= need) {
        float* featT = (float*)d_ws;
        dim3 tgrid(P_ / 32, C_ / 32, B);
        dim3 tblock(32, 8, 1);
        nchw_to_nhwc_kernel<<<tgrid, tblock, 0, stream>>>(feat, featT);

        roi_align_nhwc_kernel<<<N, 256, 0, stream>>>(rois, featT, stride_ptr, out, N);
    } else {
        const int total = N * C_ * POOLED * POOLED;
        const int block = 256;
        const int grid = (total + block - 1) / block;
        roi_align_kernel<<<grid, block, 0, stream>>>(rois, feat, stride_ptr,
                                                     B, C_, H_, W_, N, out);
    }
}

// Round 3
// 215.215 us; speedup vs baseline: 1.4288x; 1.3962x over previous
//
#include <hip/hip_runtime.h>

#define POOLED 7
#define RATIO 2

constexpr int C_ = 256;
constexpr int H_ = 192;
constexpr int W_ = 192;
constexpr int P_ = H_ * W_;   // pixels per plane
constexpr int PP2 = POOLED * POOLED;  // 49

// ---------------- NCHW -> NHWC transpose, float4 both sides ----------------
// Tile: 32 channels x 128 pixels (16 KB). Block = 256 threads.
constexpr int TC = 32;
constexpr int TP = 128;
constexpr int TPAD = TP + 1;   // +1 float pad: LDS banks ~conflict-free

__global__ __launch_bounds__(256)
void nchw_to_nhwc_v2(const float* __restrict__ in, float* __restrict__ outT) {
    __shared__ float tile[TC][TPAD];
    const int b  = blockIdx.z;
    const int p0 = blockIdx.x * TP;
    const int c0 = blockIdx.y * TC;
    const float* src = in   + (size_t)b * C_ * P_;
    float*       dst = outT + (size_t)b * P_ * C_;

    const int t = threadIdx.x;

    // Load: 32 rows x 32 float4 = 1024 float4; 4 per thread.
    #pragma unroll
    for (int k = 0; k < 4; ++k) {
        const int q  = t + 256 * k;        // 0..1023
        const int c  = q >> 5;             // 0..31
        const int pv = q & 31;             // 0..31
        const float4 v = *(const float4*)&src[(size_t)(c0 + c) * P_ + p0 + 4 * pv];
        tile[c][4 * pv + 0] = v.x;
        tile[c][4 * pv + 1] = v.y;
        tile[c][4 * pv + 2] = v.z;
        tile[c][4 * pv + 3] = v.w;
    }
    __syncthreads();

    // Store: for each pixel p, write 32 channels as 8 float4 per row.
    #pragma unroll
    for (int k = 0; k < 4; ++k) {
        const int q  = t + 256 * k;        // 0..1023
        const int p  = q >> 3;             // 0..127
        const int c4 = (q & 7) * 4;        // 0..28
        float4 v;
        v.x = tile[c4 + 0][p];
        v.y = tile[c4 + 1][p];
        v.z = tile[c4 + 2][p];
        v.w = tile[c4 + 3][p];
        *(float4*)&dst[(size_t)(p0 + p) * C_ + c0 + c4] = v;
    }
}

// ---------------- RoIAlign on NHWC feature, LDS-staged output --------------
__global__ __launch_bounds__(256)
void roi_align_nhwc_kernel(const float* __restrict__ rois,
                           const float* __restrict__ featT,   // (B,H,W,C)
                           const int* __restrict__ stride_ptr,
                           float* __restrict__ out, int N) {
    __shared__ float lds_out[C_ * PP2];    // 50176 B

    const int n    = blockIdx.x;
    const int lane = threadIdx.x & 63;
    const int wave = threadIdx.x >> 6;

    const float scale = 1.0f / (float)stride_ptr[0];
    const float* r = rois + (size_t)n * 5;
    const int   b  = (int)r[0];
    const float x1 = r[1] * scale;
    const float y1 = r[2] * scale;
    const float x2 = r[3] * scale;
    const float y2 = r[4] * scale;
    const float bin_w = fmaxf(x2 - x1, 1.0f) * (1.0f / (float)POOLED);
    const float bin_h = fmaxf(y2 - y1, 1.0f) * (1.0f / (float)POOLED);

    const float4* fbase = (const float4*)featT + (size_t)b * P_ * (C_ / 4);
    const int cb = lane * 4;

    for (int bin = wave; bin < PP2; bin += 4) {
        const int ph = bin / POOLED;
        const int pw = bin - ph * POOLED;

        float4 acc = make_float4(0.f, 0.f, 0.f, 0.f);

        #pragma unroll
        for (int sy = 0; sy < RATIO; ++sy) {
            const float yy = y1 + ((float)(ph * RATIO + sy) + 0.5f) * (1.0f / RATIO) * bin_h;
            const bool  vy = (yy > -1.0f) && (yy < (float)H_);
            float cy = fminf(fmaxf(yy, 0.0f), (float)(H_ - 1));
            int   y0 = (int)floorf(cy);
            if (y0 > H_ - 1) y0 = H_ - 1;
            const int   y1i = min(y0 + 1, H_ - 1);
            const float fy  = cy - (float)y0;
            const float hy  = 1.0f - fy;

            #pragma unroll
            for (int sx = 0; sx < RATIO; ++sx) {
                const float xx = x1 + ((float)(pw * RATIO + sx) + 0.5f) * (1.0f / RATIO) * bin_w;
                const bool  vx = (xx > -1.0f) && (xx < (float)W_);
                if (!(vy && vx)) continue;
                float cx = fminf(fmaxf(xx, 0.0f), (float)(W_ - 1));
                int   x0 = (int)floorf(cx);
                if (x0 > W_ - 1) x0 = W_ - 1;
                const int   x1i = min(x0 + 1, W_ - 1);
                const float fx  = cx - (float)x0;
                const float hx  = 1.0f - fx;

                const float w00 = hy * hx, w01 = hy * fx, w10 = fy * hx, w11 = fy * fx;

                const float4 v00 = fbase[(size_t)(y0  * W_ + x0 ) * (C_ / 4) + lane];
                const float4 v01 = fbase[(size_t)(y0  * W_ + x1i) * (C_ / 4) + lane];
                const float4 v10 = fbase[(size_t)(y1i * W_ + x0 ) * (C_ / 4) + lane];
                const float4 v11 = fbase[(size_t)(y1i * W_ + x1i) * (C_ / 4) + lane];

                acc.x = fmaf(w00, v00.x, fmaf(w01, v01.x, fmaf(w10, v10.x, fmaf(w11, v11.x, acc.x))));
                acc.y = fmaf(w00, v00.y, fmaf(w01, v01.y, fmaf(w10, v10.y, fmaf(w11, v11.y, acc.y))));
                acc.z = fmaf(w00, v00.z, fmaf(w01, v01.z, fmaf(w10, v10.z, fmaf(w11, v11.z, acc.z))));
                acc.w = fmaf(w00, v00.w, fmaf(w01, v01.w, fmaf(w10, v10.w, fmaf(w11, v11.w, acc.w))));
            }
        }

        lds_out[(cb + 0) * PP2 + bin] = acc.x * 0.25f;
        lds_out[(cb + 1) * PP2 + bin] = acc.y * 0.25f;
        lds_out[(cb + 2) * PP2 + bin] = acc.z * 0.25f;
        lds_out[(cb + 3) * PP2 + bin] = acc.w * 0.25f;
    }

    __syncthreads();

    // Block-wide contiguous copy: 12544 floats = 3136 float4.
    float4* o4 = (float4*)(out + (size_t)n * (C_ * PP2));
    const float4* l4 = (const float4*)lds_out;
    for (int i = threadIdx.x; i < (C_ * PP2) / 4; i += 256) {
        o4[i] = l4[i];
    }
}

// ---------------- Fallback (round-1, NCHW direct) ---------------------------
__global__ __launch_bounds__(256)
void roi_align_kernel(const float* __restrict__ rois,
                      const float* __restrict__ feat,
                      const int* __restrict__ stride_ptr,
                      int B, int C, int H, int W, int N,
                      float* __restrict__ out) {
    const int total = N * C * POOLED * POOLED;
    int idx = blockIdx.x * blockDim.x + threadIdx.x;
    if (idx >= total) return;

    const float scale = 1.0f / (float)stride_ptr[0];

    int pw = idx % POOLED;
    int ph = (idx / POOLED) % POOLED;
    int c  = (idx / (POOLED * POOLED)) % C;
    int n  = idx / (POOLED * POOLED * C);

    const float* r = rois + (size_t)n * 5;
    int b = (int)r[0];
    float x1 = r[1] * scale;
    float y1 = r[2] * scale;
    float x2 = r[3] * scale;
    float y2 = r[4] * scale;
    float bin_w = fmaxf(x2 - x1, 1.0f) / (float)POOLED;
    float bin_h = fmaxf(y2 - y1, 1.0f) / (float)POOLED;

    const float* plane = feat + ((size_t)b * C + c) * (size_t)(H * W);

    float acc = 0.0f;
    #pragma unroll
    for (int sy = 0; sy < RATIO; ++sy) {
        float iy = ((float)(ph * RATIO + sy) + 0.5f) / (float)RATIO;
        float yy = y1 + iy * bin_h;
        bool vy = (yy > -1.0f) && (yy < (float)H);
        float cy = fminf(fmaxf(yy, 0.0f), (float)(H - 1));
        int y0 = (int)floorf(cy);
        if (y0 > H - 1) y0 = H - 1;
        int y1i = min(y0 + 1, H - 1);
        float fy = cy - (float)y0;
        float hy = 1.0f - fy;

        #pragma unroll
        for (int sx = 0; sx < RATIO; ++sx) {
            float ix = ((float)(pw * RATIO + sx) + 0.5f) / (float)RATIO;
            float xx = x1 + ix * bin_w;
            bool vx = (xx > -1.0f) && (xx < (float)W);
            if (!(vy && vx)) continue;
            float cx = fminf(fmaxf(xx, 0.0f), (float)(W - 1));
            int x0 = (int)floorf(cx);
            if (x0 > W - 1) x0 = W - 1;
            int x1i = min(x0 + 1, W - 1);
            float fx = cx - (float)x0;
            float hx = 1.0f - fx;

            float v00 = plane[y0  * W + x0 ];
            float v01 = plane[y0  * W + x1i];
            float v10 = plane[y1i * W + x0 ];
            float v11 = plane[y1i * W + x1i];

            acc += hy * hx * v00 + hy * fx * v01 + fy * hx * v10 + fy * fx * v11;
        }
    }

    out[idx] = acc * 0.25f;
}

extern "C" void kernel_launch(void* const* d_in, const int* in_sizes, int n_in,
                              void* d_out, int out_size, void* d_ws, size_t ws_size,
                              hipStream_t stream) {
    const float* rois = (const float*)d_in[0];
    const float* feat = (const float*)d_in[1];
    const int* stride_ptr = (const int*)d_in[2];

    const int N = in_sizes[0] / 5;
    const int B = in_sizes[1] / (C_ * P_);
    float* out = (float*)d_out;

    const size_t need = (size_t)B * P_ * C_ * sizeof(float);
    if (ws_size >= need) {
        float* featT = (float*)d_ws;
        dim3 tgrid(P_ / TP, C_ / TC, B);
        nchw_to_nhwc_v2<<<tgrid, 256, 0, stream>>>(feat, featT);

        roi_align_nhwc_kernel<<<N, 256, 0, stream>>>(rois, featT, stride_ptr, out, N);
    } else {
        const int total = N * C_ * POOLED * POOLED;
        const int block = 256;
        const int grid = (total + block - 1) / block;
        roi_align_kernel<<<grid, block, 0, stream>>>(rois, feat, stride_ptr,
                                                     B, C_, H_, W_, N, out);
    }
}

// Round 4
// 167.925 us; speedup vs baseline: 1.8312x; 1.2816x over previous
//
#include <hip/hip_runtime.h>
#include <hip/hip_fp16.h>

#define POOLED 7
#define RATIO 2

constexpr int C_ = 256;
constexpr int H_ = 192;
constexpr int W_ = 192;
constexpr int P_ = H_ * W_;           // pixels per plane
constexpr int PP2 = POOLED * POOLED;  // 49

// ---------------- NCHW fp32 -> NHWC fp16 transpose -------------------------
// Tile: 32 channels x 128 pixels. Block = 256 threads.
constexpr int TC = 32;
constexpr int TP = 128;
constexpr int TPAD = TP + 1;

__global__ __launch_bounds__(256)
void nchw_to_nhwc_h(const float* __restrict__ in, __half* __restrict__ outT) {
    __shared__ float tile[TC][TPAD];
    const int b  = blockIdx.z;
    const int p0 = blockIdx.x * TP;
    const int c0 = blockIdx.y * TC;
    const float* src = in   + (size_t)b * C_ * P_;
    __half*      dst = outT + (size_t)b * P_ * C_;

    const int t = threadIdx.x;

    // Load: 32 channel-rows x 128 pixels as float4 (32 f4 per row).
    #pragma unroll
    for (int k = 0; k < 4; ++k) {
        const int q  = t + 256 * k;        // 0..1023
        const int c  = q >> 5;             // 0..31
        const int pv = q & 31;             // 0..31
        const float4 v = *(const float4*)&src[(size_t)(c0 + c) * P_ + p0 + 4 * pv];
        tile[c][4 * pv + 0] = v.x;
        tile[c][4 * pv + 1] = v.y;
        tile[c][4 * pv + 2] = v.z;
        tile[c][4 * pv + 3] = v.w;
    }
    __syncthreads();

    // Store: per pixel, 32 channels as 4 x (8 halves = 16 B).
    #pragma unroll
    for (int k = 0; k < 2; ++k) {
        const int q  = t + 256 * k;        // 0..511
        const int p  = q >> 2;             // 0..127
        const int c8 = (q & 3) * 8;        // 0,8,16,24
        union { __half h[8]; float4 f; } u;
        #pragma unroll
        for (int i = 0; i < 8; ++i) u.h[i] = __float2half(tile[c8 + i][p]);
        *(float4*)&dst[(size_t)(p0 + p) * C_ + c0 + c8] = u.f;
    }
}

__device__ inline float4 h4_to_f4(uint2 r) {
    const float2 a = __half22float2(*(const __half2*)&r.x);
    const float2 b = __half22float2(*(const __half2*)&r.y);
    return make_float4(a.x, a.y, b.x, b.y);
}

// ---------------- RoIAlign on NHWC fp16, LDS-staged output -----------------
// Block = 512 (8 waves). LDS 50 KB -> 3 blocks/CU = 24 waves/CU (75%).
__global__ __launch_bounds__(512)
void roi_align_nhwc_h(const float* __restrict__ rois,
                      const __half* __restrict__ featT,   // (B,H,W,C) fp16
                      const int* __restrict__ stride_ptr,
                      float* __restrict__ out, int N) {
    __shared__ float lds_out[C_ * PP2];    // 50176 B

    const int n    = blockIdx.x;
    const int lane = threadIdx.x & 63;
    const int wave = threadIdx.x >> 6;     // 0..7

    const float scale = 1.0f / (float)stride_ptr[0];
    const float* r = rois + (size_t)n * 5;
    const int   b  = (int)r[0];
    const float x1 = r[1] * scale;
    const float y1 = r[2] * scale;
    const float x2 = r[3] * scale;
    const float y2 = r[4] * scale;
    const float bin_w = fmaxf(x2 - x1, 1.0f) * (1.0f / (float)POOLED);
    const float bin_h = fmaxf(y2 - y1, 1.0f) * (1.0f / (float)POOLED);

    const uint2* fbase = (const uint2*)featT + (size_t)b * P_ * (C_ / 4);
    const int cb = lane * 4;

    for (int bin = wave; bin < PP2; bin += 8) {
        const int ph = bin / POOLED;
        const int pw = bin - ph * POOLED;

        float4 acc = make_float4(0.f, 0.f, 0.f, 0.f);

        #pragma unroll
        for (int sy = 0; sy < RATIO; ++sy) {
            const float yy = y1 + ((float)(ph * RATIO + sy) + 0.5f) * (1.0f / RATIO) * bin_h;
            const bool  vy = (yy > -1.0f) && (yy < (float)H_);
            float cy = fminf(fmaxf(yy, 0.0f), (float)(H_ - 1));
            int   y0 = (int)floorf(cy);
            if (y0 > H_ - 1) y0 = H_ - 1;
            const int   y1i = min(y0 + 1, H_ - 1);
            const float fy  = cy - (float)y0;
            const float hy  = 1.0f - fy;

            #pragma unroll
            for (int sx = 0; sx < RATIO; ++sx) {
                const float xx = x1 + ((float)(pw * RATIO + sx) + 0.5f) * (1.0f / RATIO) * bin_w;
                const bool  vx = (xx > -1.0f) && (xx < (float)W_);
                if (!(vy && vx)) continue;
                float cx = fminf(fmaxf(xx, 0.0f), (float)(W_ - 1));
                int   x0 = (int)floorf(cx);
                if (x0 > W_ - 1) x0 = W_ - 1;
                const int   x1i = min(x0 + 1, W_ - 1);
                const float fx  = cx - (float)x0;
                const float hx  = 1.0f - fx;

                const float w00 = hy * hx, w01 = hy * fx, w10 = fy * hx, w11 = fy * fx;

                const float4 v00 = h4_to_f4(fbase[(size_t)(y0  * W_ + x0 ) * (C_ / 4) + lane]);
                const float4 v01 = h4_to_f4(fbase[(size_t)(y0  * W_ + x1i) * (C_ / 4) + lane]);
                const float4 v10 = h4_to_f4(fbase[(size_t)(y1i * W_ + x0 ) * (C_ / 4) + lane]);
                const float4 v11 = h4_to_f4(fbase[(size_t)(y1i * W_ + x1i) * (C_ / 4) + lane]);

                acc.x = fmaf(w00, v00.x, fmaf(w01, v01.x, fmaf(w10, v10.x, fmaf(w11, v11.x, acc.x))));
                acc.y = fmaf(w00, v00.y, fmaf(w01, v01.y, fmaf(w10, v10.y, fmaf(w11, v11.y, acc.y))));
                acc.z = fmaf(w00, v00.z, fmaf(w01, v01.z, fmaf(w10, v10.z, fmaf(w11, v11.z, acc.z))));
                acc.w = fmaf(w00, v00.w, fmaf(w01, v01.w, fmaf(w10, v10.w, fmaf(w11, v11.w, acc.w))));
            }
        }

        lds_out[(cb + 0) * PP2 + bin] = acc.x * 0.25f;
        lds_out[(cb + 1) * PP2 + bin] = acc.y * 0.25f;
        lds_out[(cb + 2) * PP2 + bin] = acc.z * 0.25f;
        lds_out[(cb + 3) * PP2 + bin] = acc.w * 0.25f;
    }

    __syncthreads();

    // Block-wide contiguous copy out: 12544 floats = 3136 float4.
    float4* o4 = (float4*)(out + (size_t)n * (C_ * PP2));
    const float4* l4 = (const float4*)lds_out;
    for (int i = threadIdx.x; i < (C_ * PP2) / 4; i += 512) {
        o4[i] = l4[i];
    }
}

// ---------------- Fallback (NCHW direct, fp32) ------------------------------
__global__ __launch_bounds__(256)
void roi_align_kernel(const float* __restrict__ rois,
                      const float* __restrict__ feat,
                      const int* __restrict__ stride_ptr,
                      int B, int C, int H, int W, int N,
                      float* __restrict__ out) {
    const int total = N * C * POOLED * POOLED;
    int idx = blockIdx.x * blockDim.x + threadIdx.x;
    if (idx >= total) return;

    const float scale = 1.0f / (float)stride_ptr[0];

    int pw = idx % POOLED;
    int ph = (idx / POOLED) % POOLED;
    int c  = (idx / (POOLED * POOLED)) % C;
    int n  = idx / (POOLED * POOLED * C);

    const float* r = rois + (size_t)n * 5;
    int b = (int)r[0];
    float x1 = r[1] * scale;
    float y1 = r[2] * scale;
    float x2 = r[3] * scale;
    float y2 = r[4] * scale;
    float bin_w = fmaxf(x2 - x1, 1.0f) / (float)POOLED;
    float bin_h = fmaxf(y2 - y1, 1.0f) / (float)POOLED;

    const float* plane = feat + ((size_t)b * C + c) * (size_t)(H * W);

    float acc = 0.0f;
    #pragma unroll
    for (int sy = 0; sy < RATIO; ++sy) {
        float iy = ((float)(ph * RATIO + sy) + 0.5f) / (float)RATIO;
        float yy = y1 + iy * bin_h;
        bool vy = (yy > -1.0f) && (yy < (float)H);
        float cy = fminf(fmaxf(yy, 0.0f), (float)(H - 1));
        int y0 = (int)floorf(cy);
        if (y0 > H - 1) y0 = H - 1;
        int y1i = min(y0 + 1, H - 1);
        float fy = cy - (float)y0;
        float hy = 1.0f - fy;

        #pragma unroll
        for (int sx = 0; sx < RATIO; ++sx) {
            float ix = ((float)(pw * RATIO + sx) + 0.5f) / (float)RATIO;
            float xx = x1 + ix * bin_w;
            bool vx = (xx > -1.0f) && (xx < (float)W);
            if (!(vy && vx)) continue;
            float cx = fminf(fmaxf(xx, 0.0f), (float)(W - 1));
            int x0 = (int)floorf(cx);
            if (x0 > W - 1) x0 = W - 1;
            int x1i = min(x0 + 1, W - 1);
            float fx = cx - (float)x0;
            float hx = 1.0f - fx;

            float v00 = plane[y0  * W + x0 ];
            float v01 = plane[y0  * W + x1i];
            float v10 = plane[y1i * W + x0 ];
            float v11 = plane[y1i * W + x1i];

            acc += hy * hx * v00 + hy * fx * v01 + fy * hx * v10 + fy * fx * v11;
        }
    }

    out[idx] = acc * 0.25f;
}

extern "C" void kernel_launch(void* const* d_in, const int* in_sizes, int n_in,
                              void* d_out, int out_size, void* d_ws, size_t ws_size,
                              hipStream_t stream) {
    const float* rois = (const float*)d_in[0];
    const float* feat = (const float*)d_in[1];
    const int* stride_ptr = (const int*)d_in[2];

    const int N = in_sizes[0] / 5;
    const int B = in_sizes[1] / (C_ * P_);
    float* out = (float*)d_out;

    const size_t need = (size_t)B * P_ * C_ * sizeof(__half);
    if (ws_size >= need) {
        __half* featT = (__half*)d_ws;
        dim3 tgrid(P_ / TP, C_ / TC, B);
        nchw_to_nhwc_h<<<tgrid, 256, 0, stream>>>(feat, featT);

        roi_align_nhwc_h<<<N, 512, 0, stream>>>(rois, featT, stride_ptr, out, N);
    } else {
        const int total = N * C_ * POOLED * POOLED;
        const int block = 256;
        const int grid = (total + block - 1) / block;
        roi_align_kernel<<<grid, block, 0, stream>>>(rois, feat, stride_ptr,
                                                     B, C_, H_, W_, N, out);
    }
}